// Round 7
// baseline (6718.547 us; speedup 1.0000x reference)
//
#include <hip/hip_runtime.h>
#include <cfloat>
#include <math.h>

#define N 512
#define T 256          // threads; thread t owns columns t+1 and t+257
typedef unsigned long long u64_t;

__device__ __forceinline__ u64_t map_f64(double x) {
    u64_t b = (u64_t)__double_as_longlong(x);
    return b ^ ((b >> 63) ? 0xFFFFFFFFFFFFFFFFull : 0x8000000000000000ull);
}
__device__ __forceinline__ double unmap_f64(u64_t b) {
    b ^= ((b >> 63) ? 0x8000000000000000ull : 0xFFFFFFFFFFFFFFFFull);
    return __longlong_as_double((long long)b);
}

// wave64 u64 min-reduce via DPP (VALU pipe). Valid result in lane 63.
__device__ __forceinline__ u64_t wave_min_key(u64_t key) {
    unsigned hi = (unsigned)(key >> 32), lo = (unsigned)key;
#define MIN_STAGE(CTRL)                                                        \
    {                                                                          \
        unsigned oh = (unsigned)__builtin_amdgcn_update_dpp((int)hi, (int)hi,  \
                                                            CTRL, 0xF, 0xF, false); \
        unsigned ol = (unsigned)__builtin_amdgcn_update_dpp((int)lo, (int)lo,  \
                                                            CTRL, 0xF, 0xF, false); \
        const u64_t o = ((u64_t)oh << 32) | ol;                                \
        const u64_t c = ((u64_t)hi << 32) | lo;                                \
        if (o < c) { hi = oh; lo = ol; }                                       \
    }
    MIN_STAGE(0x111) MIN_STAGE(0x112) MIN_STAGE(0x114) MIN_STAGE(0x118)
    MIN_STAGE(0x142) MIN_STAGE(0x143)
#undef MIN_STAGE
    return ((u64_t)hi << 32) | lo;
}

// rowdat[i]: .x = packed (f32 b | f32 d), .y = u[i]. One b128 read per settle.
__device__ __forceinline__ void rd_decode(const double2 rd, double& b, double& d,
                                          double& u) {
    const u64_t bits = (u64_t)__double_as_longlong(rd.x);
    b = (double)__uint_as_float((unsigned)bits);         // f32-exact widen
    d = (double)__uint_as_float((unsigned)(bits >> 32));
    u = rd.y;
}

// 256 threads / 4 waves. Exact JV: column reduction + greedy tight match +
// sequential ARR warm start + Dijkstra (R5 core, 2 cols/thread).
// key = [45b value | 9b col-1 | 10b p[col]] (truncation: absmax 0 in R3-R6).
__global__ __launch_bounds__(T, 1) void tofu_solver(
    const float* __restrict__ dgm, const float* __restrict__ dgm_x,
    float* __restrict__ out)
{
#pragma clang fp contract(off)
    __shared__ double2 rowdat[N + 1];
    __shared__ int     p_lds[N + 1];
    __shared__ int     way_lds[N + 1];
    __shared__ int     claim[N + 1];
    __shared__ int     flist[4 * N + 32];
    __shared__ u64_t   dslot[3];
    __shared__ u64_t   aslot[2], bslot[2];
    __shared__ double  v1x;
    __shared__ double  red4[4];
    __shared__ int     nfree_s;

    const int tid  = threadIdx.x;       // 0..255
    const int lane = tid & 63;
    const int wid  = tid >> 6;          // 0..3
    const int colv[2] = { tid + 1, tid + 1 + T };
    const float2* dgm2  = (const float2*)dgm;
    const float2* dgmx2 = (const float2*)dgm_x;

    // ---- stage: rows -> rowdat (u=0); own columns' points -> f64 registers ----
    #pragma unroll
    for (int c = 0; c < 2; ++c) {
        const int r = colv[c];                         // rows 1..512
        const float2 p2 = dgm2[r - 1];
        double2 rd;
        rd.x = __longlong_as_double((long long)(
                   ((u64_t)__float_as_uint(p2.y) << 32) | __float_as_uint(p2.x)));
        rd.y = 0.0;
        rowdat[r] = rd;
        p_lds[r] = 0; way_lds[r] = 0; claim[r] = 0x7fffffff;
    }
    double xb[2], xd[2];
    #pragma unroll
    for (int c = 0; c < 2; ++c) {
        const float2 q2 = dgmx2[colv[c] - 1];
        xb[c] = (double)q2.x; xd[c] = (double)q2.y;
    }
    if (tid == 0) {
        p_lds[0] = 0; way_lds[0] = 0; claim[0] = 0x7fffffff;
        dslot[0] = dslot[1] = dslot[2] = ~0ull;
        aslot[0] = aslot[1] = ~0ull; bslot[0] = bslot[1] = ~0ull;
    }
    __syncthreads();

    // ---- column reduction: v[j] = min_i c(i,j) (sq-dist argmin; sqrt monotone) ----
    double v[2]; int amin[2];
    {
        double vsq[2] = { DBL_MAX, DBL_MAX };
        amin[0] = amin[1] = 1;
        for (int i = 1; i <= N; ++i) {
            const double2 rd = rowdat[i];              // broadcast b128
            double rb, rdd, ru; rd_decode(rd, rb, rdd, ru);
            #pragma unroll
            for (int c = 0; c < 2; ++c) {
                const double db = rb - xb[c], dd = rdd - xd[c];
                const double sq = db * db + dd * dd;
                if (sq < vsq[c]) { vsq[c] = sq; amin[c] = i; }
            }
        }
        v[0] = sqrt(vsq[0]); v[1] = sqrt(vsq[1]);      // exact min of column
    }

    // ---- greedy: row r -> smallest col whose argmin is r (tight, u=0) ----
    int myp[2] = { 0, 0 };
    #pragma unroll
    for (int c = 0; c < 2; ++c) atomicMin(&claim[amin[c]], colv[c]);
    __syncthreads();
    #pragma unroll
    for (int c = 0; c < 2; ++c)
        if (claim[amin[c]] == colv[c]) { p_lds[colv[c]] = amin[c]; myp[c] = amin[c]; }
    __syncthreads();

    // ---- freelist of unmatched rows ----
    for (int c = 0; c < 2; ++c) claim[colv[c]] = 0;
    __syncthreads();
    for (int c = 0; c < 2; ++c) { const int r = p_lds[colv[c]]; if (r) claim[r] = 1; }
    __syncthreads();
    if (tid == 0) {
        int nf = 0;
        for (int r = 1; r <= N; ++r) if (!claim[r]) flist[nf++] = r;
        nfree_s = nf;
    }
    __syncthreads();

    // ---- sequential ARR (exactness-preserving, capped; R5 logic) ----
    {
        int head = 0, tail = nfree_s, q = 0;
        const int cap = 3 * tail + 16;
        for (int step = 0; step < cap && head < tail; ++step) {
            const int i = flist[head++];               // uniform broadcast
            const double2 rd = rowdat[i];
            double rb, rdd, ru; rd_decode(rd, rb, rdd, ru);
            double val[2]; u64_t key[2];
            #pragma unroll
            for (int c = 0; c < 2; ++c) {
                const double db = rb - xb[c], dd = rdd - xd[c];
                val[c] = sqrt(db * db + dd * dd) - v[c];
                key[c] = (map_f64(val[c]) & ~0x7FFFFull)
                       | ((u64_t)(colv[c] - 1) << 10) | (u64_t)myp[c];
            }
            u64_t kr = wave_min_key(key[0] < key[1] ? key[0] : key[1]);
            if (lane == 63) atomicMin(&aslot[q], kr);
            __syncthreads();
            const u64_t k1 = aslot[q];
            const int j1    = (int)((k1 >> 10) & 511) + 1;
            const int k_old = (int)(k1 & 1023);
            u64_t kmin2 = ~0ull;
            #pragma unroll
            for (int c = 0; c < 2; ++c) {
                if (colv[c] == j1) v1x = val[c];       // exact v1 handoff
                else if (key[c] < kmin2) kmin2 = key[c];
            }
            kr = wave_min_key(kmin2);
            if (lane == 63) atomicMin(&bslot[q], kr);
            __syncthreads();
            const double m2t = unmap_f64(bslot[q] & ~0x7FFFFull);  // <= true 2nd-min
            const double ui  = fmax(m2t, v1x);         // feasible AND tight on j1
            #pragma unroll
            for (int c = 0; c < 2; ++c)
                if (colv[c] == j1) { v[c] -= (ui - val[c]); myp[c] = i; }
            if (tid == 0) {
                rowdat[i].y = ui;
                p_lds[j1] = i;
                if (k_old) flist[tail] = k_old;
                aslot[q ^ 1] = ~0ull; bslot[q ^ 1] = ~0ull;  // 2 barriers since read
            }
            if (k_old) ++tail;                         // uniform
            q ^= 1;
            __syncthreads();
        }
    }

    // ---- rebuild freelist from p ----
    for (int c = 0; c < 2; ++c) claim[colv[c]] = 0;
    __syncthreads();
    for (int c = 0; c < 2; ++c) { const int r = p_lds[colv[c]]; if (r) claim[r] = 1; }
    __syncthreads();
    if (tid == 0) {
        int nf = 0;
        for (int r = 1; r <= N; ++r) if (!claim[r]) flist[nf++] = r;
        nfree_s = nf;
    }
    __syncthreads();
    const int nfree = nfree_s;

    // ---- exact Dijkstra phase ----
    for (int kk = 0; kk < nfree; ++kk) {
        const int iroot = flist[kk];
        const int pc[2] = { p_lds[colv[0]], p_lds[colv[1]] };  // static this Dijkstra
        if (tid == 0) p_lds[0] = iroot;                // augment-chain terminator
        double minv[2] = { DBL_MAX, DBL_MAX }, du[2] = { 0.0, 0.0 }, du0 = 0.0;
        int usedm = 0, juse = 0, i0 = iroot, par = 0;

        while (true) {
            if (colv[0] == juse) usedm |= 1;           // mark prev winner
            if (colv[1] == juse) usedm |= 2;
            const double2 rd = rowdat[i0];             // ONE b128: pt + u
            double rb, rdd, u0; rd_decode(rd, rb, rdd, u0);
            u64_t kmin = ~0ull;
            #pragma unroll
            for (int c = 0; c < 2; ++c) {
                if (!((usedm >> c) & 1)) {
                    const double db = rb - xb[c], dd = rdd - xd[c];
                    const double cost = sqrt(db * db + dd * dd);
                    const double cur = (cost - u0) - v[c];
                    if (cur < minv[c]) { minv[c] = cur; way_lds[colv[c]] = juse; }
                    const u64_t k = (map_f64(minv[c]) & ~0x7FFFFull)
                                  | ((u64_t)(colv[c] - 1) << 10) | (u64_t)pc[c];
                    if (k < kmin) kmin = k;
                }
            }
            kmin = wave_min_key(kmin);
            if (lane == 63) atomicMin(&dslot[par], kmin);  // 4-way combine
            __syncthreads();
            const u64_t k = dslot[par];
            if (tid == 0) dslot[(par + 2) % 3] = ~0ull;    // read 2 barriers ago
            const double delta = unmap_f64(k & ~0x7FFFFull);
            #pragma unroll
            for (int c = 0; c < 2; ++c) {
                if ((usedm >> c) & 1) { v[c] -= delta; du[c] += delta; }
                else                    minv[c] -= delta;
            }
            if (tid == 0) du0 += delta;
            juse = (int)((k >> 10) & 511) + 1;
            i0   = (int)(k & 1023);                    // p payload; 0 => free col
            if (i0 == 0) break;
            par = (par + 1) % 3;
        }

        // flush duals (matched rows distinct => race-free), augment, clean slot
        if (usedm & 1) rowdat[pc[0]].y += du[0];
        if (usedm & 2) rowdat[pc[1]].y += du[1];
        if (tid == 0) {
            rowdat[iroot].y += du0;
            dslot[par] = ~0ull;
            int j = juse;
            while (j) { const int jn = way_lds[j]; p_lds[j] = p_lds[jn]; j = jn; }
        }
        __syncthreads();
    }

    // ---- loss = 0.5 * sum_j ||dgm[p[j]-1] - dgm_x[j-1]||^2 (f32 diffs like ref) ----
    double acc = 0.0;
    #pragma unroll
    for (int c = 0; c < 2; ++c) {
        const int j = colv[c] - 1;
        const int r = p_lds[colv[c]] - 1;
        const float2 a = dgm2[r];
        const float2 b = dgmx2[j];
        const float fb = a.x - b.x;
        const float fd = a.y - b.y;
        acc += (double)fb * (double)fb + (double)fd * (double)fd;
    }
    #pragma unroll
    for (int m = 32; m >= 1; m >>= 1) acc += __shfl_xor(acc, m, 64);
    if (lane == 0) red4[wid] = acc;
    __syncthreads();
    if (tid == 0) {
        double s = 0.0;
        #pragma unroll
        for (int w = 0; w < 4; ++w) s += red4[w];
        out[0] = (float)(0.5 * s);
    }
}

extern "C" void kernel_launch(void* const* d_in, const int* in_sizes, int n_in,
                              void* d_out, int out_size, void* d_ws, size_t ws_size,
                              hipStream_t stream) {
    const float* dgm   = (const float*)d_in[0];
    const float* dgm_x = (const float*)d_in[1];
    float* out = (float*)d_out;
    tofu_solver<<<1, T, 0, stream>>>(dgm, dgm_x, out);
}